// Round 2
// baseline (702.003 us; speedup 1.0000x reference)
//
#include <hip/hip_runtime.h>
#include <hip/hip_bf16.h>

// Shapes fixed by setup_inputs(): B=2, C=128, H=256, W=448, stride=1.
#define BB 2
#define CC 128
#define HH 256
#define WW 448
#define KK 49
#define HWSZ (HH * WW)

// ---------------- Kernel 1: bilinear backwarp -> bf16 warped in ws ----------
__global__ __launch_bounds__(256) void warp_kernel(
    const float* __restrict__ two, const float* __restrict__ flow,
    __hip_bfloat16* __restrict__ warped) {
  int idx = blockIdx.x * blockDim.x + threadIdx.x;
  if (idx >= BB * HWSZ) return;
  int x = idx % WW;
  int y = (idx / WW) % HH;
  int b = idx / HWSZ;

  float fx = flow[(b * 2 + 0) * HWSZ + y * WW + x] * 2.5f;
  float fy = flow[(b * 2 + 1) * HWSZ + y * WW + x] * 2.5f;
  float px = (float)x + fx;
  float py = (float)y + fy;
  float x0f = floorf(px), y0f = floorf(py);
  int x0 = (int)x0f, y0 = (int)y0f;
  int x1 = x0 + 1, y1 = y0 + 1;
  float wx1 = px - x0f, wx0 = 1.0f - wx1;
  float wy1 = py - y0f, wy0 = 1.0f - wy1;
  bool vx0 = (x0 >= 0) && (x0 < WW);
  bool vx1 = (x1 >= 0) && (x1 < WW);
  bool vy0 = (y0 >= 0) && (y0 < HH);
  bool vy1 = (y1 >= 0) && (y1 < HH);
  float w00 = (vx0 && vy0) ? wx0 * wy0 : 0.0f;
  float w01 = (vx1 && vy0) ? wx1 * wy0 : 0.0f;
  float w10 = (vx0 && vy1) ? wx0 * wy1 : 0.0f;
  float w11 = (vx1 && vy1) ? wx1 * wy1 : 0.0f;
  int cx0 = min(max(x0, 0), WW - 1);
  int cx1 = min(max(x1, 0), WW - 1);
  int cy0 = min(max(y0, 0), HH - 1);
  int cy1 = min(max(y1, 0), HH - 1);
  int o00 = cy0 * WW + cx0;
  int o01 = cy0 * WW + cx1;
  int o10 = cy1 * WW + cx0;
  int o11 = cy1 * WW + cx1;

  const float* p = two + (size_t)b * CC * HWSZ;
  __hip_bfloat16* wo = warped + (size_t)b * CC * HWSZ + y * WW + x;
#pragma unroll 8
  for (int c = 0; c < CC; ++c) {
    float v = w00 * p[o00] + w01 * p[o01] + w10 * p[o10] + w11 * p[o11];
    *wo = __float2bfloat16(v);
    p += HWSZ;
    wo += HWSZ;
  }
}

// ---------------- Kernel 2: 7x7 correlation + leaky relu -------------------
// Block = (b, ytile of 4 rows, xtile of 224 cols). 256 threads, 224 active:
// thread = (yr = tid/56, xg = tid%56), computes PX=4 consecutive x, all 49
// displacements -> float4 acc[49]. Warped rows staged per channel into
// double-buffered LDS (f32), one barrier/channel, next channel prefetched
// into registers during compute.
#define YT 4
#define XT 224
#define NXG 56         // XT/4
#define NTHR 256
#define NACT 224
#define SROWS 10       // YT + 6
#define SCOLS 232      // XT + 8 (read slack)
#define SSTR 240       // padded LDS row stride in floats (240 % 32 = 16)
#define NSTG (SROWS * SCOLS)  // 2320
#define NK 10          // ceil(NSTG / NTHR)

__global__ __launch_bounds__(NTHR, 2) void corr_kernel(
    const float* __restrict__ one, const __hip_bfloat16* __restrict__ warped,
    float* __restrict__ out) {
  __shared__ float wlds[2][SROWS * SSTR];

  int bx = blockIdx.x;
  int b = bx >> 7;
  int rest = bx & 127;
  int ytile = rest >> 1;
  int xtile = rest & 1;
  int ybase = ytile * YT;
  int X0 = xtile * XT;

  int tid = threadIdx.x;

  // Per-thread staging descriptors (loop-invariant).
  int bo[NK];          // global spatial offset yy*WW+xw
  int la[NK];          // LDS float offset r*SSTR+col
  unsigned vmask = 0;
#pragma unroll
  for (int k = 0; k < NK; ++k) {
    int i = tid + k * NTHR;
    int r = i / SCOLS;
    int col = i - r * SCOLS;
    int yy = ybase - 3 + r;
    int xw = X0 - 4 + col;
    bool v = (i < NSTG) && (yy >= 0) && (yy < HH) && (xw >= 0) && (xw < WW);
    if (v) vmask |= (1u << k);
    bo[k] = yy * WW + xw;
    la[k] = r * SSTR + col;
  }

  bool active = (tid < NACT);
  int yr = tid / NXG;
  int xg = tid - yr * NXG;
  int xb = xg * 4;
  int y = ybase + yr;

  const __hip_bfloat16* wbase = warped + (size_t)b * CC * HWSZ;
  const float4* onep = nullptr;
  if (active)
    onep = (const float4*)(one + ((size_t)(b * CC) * HH + y) * WW + X0 + xb);

  float4 acc[KK];
#pragma unroll
  for (int k = 0; k < KK; ++k) acc[k] = make_float4(0.f, 0.f, 0.f, 0.f);

  // Prologue: stage channel 0 into buffer 0.
#pragma unroll
  for (int k = 0; k < NK; ++k) {
    float v = 0.f;
    if (vmask & (1u << k)) v = __bfloat162float(wbase[bo[k]]);
    if (tid + k * NTHR < NSTG) wlds[0][la[k]] = v;
  }
  float4 one_nxt = make_float4(0.f, 0.f, 0.f, 0.f);
  if (active) one_nxt = onep[0];

  int cur = 0;
  for (int c = 0; c < CC; ++c) {
    __syncthreads();  // buf[cur] staged & visible
    float4 o4 = one_nxt;
    int cn = (c + 1 < CC) ? (c + 1) : (CC - 1);

    // Issue next channel's staging loads (latency hidden under compute).
    float nv[NK];
#pragma unroll
    for (int k = 0; k < NK; ++k) {
      nv[k] = 0.f;
      if (vmask & (1u << k))
        nv[k] = __bfloat162float(wbase[(size_t)cn * HWSZ + bo[k]]);
    }

    if (active) {
      one_nxt = onep[(size_t)cn * (HWSZ / 4)];
      const float* lbase = &wlds[cur][yr * SSTR + xb];
#pragma unroll
      for (int dj = 0; dj < 7; ++dj) {
        const float* row = lbase + dj * SSTR;
        float4 wa = *(const float4*)(row);
        float4 wb = *(const float4*)(row + 4);
        float4 wc = *(const float4*)(row + 8);
        float wr[12] = {wa.x, wa.y, wa.z, wa.w, wb.x, wb.y, wb.z, wb.w,
                        wc.x, wc.y, wc.z, wc.w};
#pragma unroll
        for (int di = 0; di < 7; ++di) {
          float4& a = acc[dj * 7 + di];
          a.x += o4.x * wr[di + 1];
          a.y += o4.y * wr[di + 2];
          a.z += o4.z * wr[di + 3];
          a.w += o4.w * wr[di + 4];
        }
      }
    }

    // Write prefetched channel into the other buffer (no barrier needed:
    // nobody reads it until the next loop-top barrier).
    int nb = cur ^ 1;
#pragma unroll
    for (int k = 0; k < NK; ++k) {
      if (tid + k * NTHR < NSTG) wlds[nb][la[k]] = nv[k];
    }
    cur = nb;
  }

  if (active) {
    float* ob = out + ((size_t)(b * KK) * HH + y) * WW + X0 + xb;
#pragma unroll
    for (int k = 0; k < KK; ++k) {
      float4 v = acc[k];
      v.x *= (1.f / 128.f);
      v.y *= (1.f / 128.f);
      v.z *= (1.f / 128.f);
      v.w *= (1.f / 128.f);
      v.x = (v.x > 0.f) ? v.x : v.x * 0.1f;
      v.y = (v.y > 0.f) ? v.y : v.y * 0.1f;
      v.z = (v.z > 0.f) ? v.z : v.z * 0.1f;
      v.w = (v.w > 0.f) ? v.w : v.w * 0.1f;
      *(float4*)(ob + (size_t)k * HWSZ) = v;
    }
  }
}

// ---------------- launch ----------------------------------------------------
extern "C" void kernel_launch(void* const* d_in, const int* in_sizes, int n_in,
                              void* d_out, int out_size, void* d_ws,
                              size_t ws_size, hipStream_t stream) {
  const float* tenOne = (const float*)d_in[0];
  const float* tenTwo = (const float*)d_in[1];
  const float* tenFlow = (const float*)d_in[2];

  __hip_bfloat16* warped = (__hip_bfloat16*)d_ws;  // B*C*H*W bf16

  {
    int total = BB * HWSZ;
    int threads = 256;
    int blocks = (total + threads - 1) / threads;
    warp_kernel<<<blocks, threads, 0, stream>>>(tenTwo, tenFlow, warped);
  }
  {
    int blocks = BB * (HH / YT) * (WW / XT);  // 2 * 64 * 2 = 256
    corr_kernel<<<blocks, NTHR, 0, stream>>>(tenOne, warped, (float*)d_out);
  }
}

// Round 3
// 379.693 us; speedup vs baseline: 1.8489x; 1.8489x over previous
//
#include <hip/hip_runtime.h>
#include <hip/hip_bf16.h>

// Shapes fixed by setup_inputs(): B=2, C=128, H=256, W=448, stride=1.
#define BB 2
#define CC 128
#define HH 256
#define WW 448
#define KK 49
#define HWSZ (HH * WW)
#define PW 456  // padded width of warped_t: px = x+4, x in [-4, 452)

typedef __attribute__((ext_vector_type(8))) short bf16x8;
typedef __attribute__((ext_vector_type(4))) float f32x4;
typedef __attribute__((ext_vector_type(8))) unsigned short u16x8;

static __device__ __forceinline__ short f2bf(float v) {
  __hip_bfloat16 h = __float2bfloat16(v);
  return *reinterpret_cast<short*>(&h);
}

// ---------------- Kernel 0: zero the x-padding borders of warped_t ----------
// px in {0,1,2,3, 452,453,454,455} for all (b,y), full C. 1 MB total.
__global__ __launch_bounds__(256) void border_kernel(__hip_bfloat16* wt) {
  int i = blockIdx.x * 256 + threadIdx.x;  // 65536
  int by = i >> 7;                         // b*HH + y, 0..511
  int r = i & 127;
  int ps = r >> 4;  // 0..7
  int c16 = r & 15;
  int px = (ps < 4) ? ps : (448 + ps);
  u16x8 z = {0, 0, 0, 0, 0, 0, 0, 0};
  *(u16x8*)((char*)wt + ((size_t)((size_t)by * PW + px) * CC + c16 * 8) * 2) = z;
}

// ---------------- Kernel 1: bilinear backwarp -> warped_t[b][y][px][c] bf16 -
__global__ __launch_bounds__(256) void warp_kernel(
    const float* __restrict__ two, const float* __restrict__ flow,
    __hip_bfloat16* __restrict__ wt) {
  int idx = blockIdx.x * 256 + threadIdx.x;
  if (idx >= BB * HWSZ) return;
  int x = idx % WW;
  int y = (idx / WW) % HH;
  int b = idx / HWSZ;

  float fx = flow[(b * 2 + 0) * HWSZ + y * WW + x] * 2.5f;
  float fy = flow[(b * 2 + 1) * HWSZ + y * WW + x] * 2.5f;
  float px = (float)x + fx;
  float py = (float)y + fy;
  float x0f = floorf(px), y0f = floorf(py);
  int x0 = (int)x0f, y0 = (int)y0f;
  int x1 = x0 + 1, y1 = y0 + 1;
  float wx1 = px - x0f, wx0 = 1.0f - wx1;
  float wy1 = py - y0f, wy0 = 1.0f - wy1;
  bool vx0 = (x0 >= 0) && (x0 < WW);
  bool vx1 = (x1 >= 0) && (x1 < WW);
  bool vy0 = (y0 >= 0) && (y0 < HH);
  bool vy1 = (y1 >= 0) && (y1 < HH);
  float w00 = (vx0 && vy0) ? wx0 * wy0 : 0.0f;
  float w01 = (vx1 && vy0) ? wx1 * wy0 : 0.0f;
  float w10 = (vx0 && vy1) ? wx0 * wy1 : 0.0f;
  float w11 = (vx1 && vy1) ? wx1 * wy1 : 0.0f;
  int cx0 = min(max(x0, 0), WW - 1);
  int cx1 = min(max(x1, 0), WW - 1);
  int cy0 = min(max(y0, 0), HH - 1);
  int cy1 = min(max(y1, 0), HH - 1);
  int o00 = cy0 * WW + cx0;
  int o01 = cy0 * WW + cx1;
  int o10 = cy1 * WW + cx0;
  int o11 = cy1 * WW + cx1;

  const float* p = two + (size_t)b * CC * HWSZ;
  char* wo = (char*)wt + ((size_t)((size_t)(b * HH + y) * PW) + x + 4) * CC * 2;
#pragma unroll 4
  for (int j = 0; j < 16; ++j) {
    u16x8 pk;
#pragma unroll
    for (int jj = 0; jj < 8; ++jj) {
      int c = j * 8 + jj;
      const float* pc = p + (size_t)c * HWSZ;
      float v = w00 * pc[o00] + w01 * pc[o01] + w10 * pc[o10] + w11 * pc[o11];
      pk[jj] = (unsigned short)f2bf(v);
    }
    *(u16x8*)(wo + j * 16) = pk;
  }
}

// ---------------- Kernel 2: correlation via MFMA ----------------------------
// Wave = one (b, y, 16-px x-tile). D[x_local][pos] = sum_c A·B over 22
// positions; band pos = x_local + di gives all 49 displacements.
// acc[7 dj][2 ntile] f32x4. No LDS, no barriers.
__global__ __launch_bounds__(256) void corr_kernel(
    const float* __restrict__ one, const __hip_bfloat16* __restrict__ wt,
    float* __restrict__ out) {
  int bid = blockIdx.x;                       // 3584 = 8 * 448
  int wgid = (bid & 7) * 448 + (bid >> 3);    // XCD swizzle (bijective)
  int b = wgid / 1792;
  int rem = wgid - b * 1792;
  int xt = rem >> 6;   // 0..27
  int yg = rem & 63;   // 0..63
  int w = threadIdx.x >> 6;  // wave 0..3
  int l = threadIdx.x & 63;
  int lp = l & 15;
  int lg = l >> 4;
  int y = yg * 4 + w;
  int X0 = xt * 16;

  // A: one[b][c][y][X0+lp], c = t*32 + lg*8 + j
  const float* Abase = one + ((size_t)(b * CC) * HH + y) * WW + X0 + lp;
  // B: wt[b][y+dj-3][X0+1+pos][c], pos = min(lp+16*nt, 21)
  int pos1 = (lp + 16 < 21) ? (lp + 16) : 21;
  const char* Bb = (const char*)wt + (size_t)(b * HH) * PW * CC * 2;
  size_t pxo0 = (size_t)(X0 + 1 + lp) * CC * 2;
  size_t pxo1 = (size_t)(X0 + 1 + pos1) * CC * 2;

  f32x4 acc[7][2] = {};

#pragma unroll
  for (int t = 0; t < 4; ++t) {
    bf16x8 a;
#pragma unroll
    for (int j = 0; j < 8; ++j) {
      float v = Abase[(size_t)(t * 32 + lg * 8 + j) * HWSZ];
      a[j] = f2bf(v);
    }
    size_t coff = (size_t)(t * 32 + lg * 8) * 2;
#pragma unroll
    for (int dj = 0; dj < 7; ++dj) {
      int yy = y + dj - 3;
      if (yy < 0 || yy >= HH) continue;  // wave-uniform: zero contribution
      const char* rb = Bb + (size_t)yy * PW * CC * 2 + coff;
      bf16x8 b0 = *(const bf16x8*)(rb + pxo0);
      bf16x8 b1 = *(const bf16x8*)(rb + pxo1);
      acc[dj][0] =
          __builtin_amdgcn_mfma_f32_16x16x32_bf16(a, b0, acc[dj][0], 0, 0, 0);
      acc[dj][1] =
          __builtin_amdgcn_mfma_f32_16x16x32_bf16(a, b1, acc[dj][1], 0, 0, 0);
    }
  }

  // Epilogue: D col = lane&15 (+16*nt) = pos, row = 4*(lane>>4)+reg = x_local.
  // out[(b*49 + dj*7 + di)][y][X0 + x_local], di = pos - x_local in [0,6].
  float* obase = out + ((size_t)(b * KK) * HH + y) * WW + X0;
#pragma unroll
  for (int dj = 0; dj < 7; ++dj) {
    float* od = obase + (size_t)(dj * 7) * HWSZ;
#pragma unroll
    for (int nt = 0; nt < 2; ++nt) {
      int post = lp + 16 * nt;  // true (unclamped) position
#pragma unroll
      for (int r = 0; r < 4; ++r) {
        int xlc = 4 * lg + r;
        int di = post - xlc;
        float v = acc[dj][nt][r] * (1.0f / 128.0f);
        v = (v > 0.0f) ? v : 0.1f * v;
        if (di >= 0 && di <= 6) od[(size_t)di * HWSZ + xlc] = v;
      }
    }
  }
}

// ---------------- launch ----------------------------------------------------
extern "C" void kernel_launch(void* const* d_in, const int* in_sizes, int n_in,
                              void* d_out, int out_size, void* d_ws,
                              size_t ws_size, hipStream_t stream) {
  const float* tenOne = (const float*)d_in[0];
  const float* tenTwo = (const float*)d_in[1];
  const float* tenFlow = (const float*)d_in[2];

  __hip_bfloat16* warped_t = (__hip_bfloat16*)d_ws;  // 2*256*456*128 bf16 = 57 MB

  border_kernel<<<256, 256, 0, stream>>>(warped_t);
  {
    int total = BB * HWSZ;
    int blocks = (total + 255) / 256;
    warp_kernel<<<blocks, 256, 0, stream>>>(tenTwo, tenFlow, warped_t);
  }
  corr_kernel<<<3584, 256, 0, stream>>>(tenOne, warped_t, (float*)d_out);
}